// Round 3
// baseline (388.195 us; speedup 1.0000x reference)
//
#include <hip/hip_runtime.h>
#include <hip/hip_bf16.h>
#include <hip/hip_fp16.h>

// GNN layer: out = segment_sum(edge_vals * h[edge_cols], edge_rows), h = x @ W
// N=100000 nodes, E=1.6M edges, D=128.
//
// R8: R6->R7 removed 4x decode redundancy at ZERO time change -> pass 2 is
// latency-bound on the scattered h-gather, not VALU-bound. The gather loop
// drained vmcnt to 0 every 8 edges AND at every row boundary (~16 edges).
// Fix: each wave's 8 rows are a contiguous srt segment; stream it with
// ping-pong 8-batches (issue B's gathers while consuming A; row transitions
// handled in consume via wave-uniform compare) -> ~16 outstanding gathers
// continuously. VGPR ~50, pinned by __launch_bounds__(1024,8).
// Also: fuse GEMM + part (independent) into one %3-interleaved dispatch to
// overlap MFMA-heavy with memory-heavy blocks and drop a launch gap.

#define DIM 128
#define RB 128        // rows per bucket (pass-1 partition granularity)
#define NB_MAX 1024   // max buckets supported by pass1 LDS arrays
#define CH 4096       // edges per pass1 block
#define REG_CAP 2560  // records per bucket region (mean 2048, +11 sigma)

typedef short s16x8 __attribute__((ext_vector_type(8)));
typedef float f32x4 __attribute__((ext_vector_type(4)));
typedef unsigned short u16;
typedef unsigned long long u64;
typedef u16 u16x4 __attribute__((ext_vector_type(4)));
typedef u16 u16x8 __attribute__((ext_vector_type(8)));

static __device__ __forceinline__ u16 f2bf(float f) {
  union { float f; unsigned u; } a; a.f = f;
  return (u16)((a.u + 0x7fffu + ((a.u >> 16) & 1u)) >> 16);
}
static __device__ __forceinline__ float bf_lo(unsigned u) {
  union { unsigned u; float f; } a; a.u = u << 16; return a.f;
}
static __device__ __forceinline__ float bf_hi(unsigned u) {
  union { unsigned u; float f; } a; a.u = u & 0xffff0000u; return a.f;
}
static __device__ __forceinline__ u16 f2h(float f) {
  return __half_as_ushort(__float2half(f));
}
static __device__ __forceinline__ float h2f(u16 h) {
  return __half2float(__ushort_as_half(h));
}

// ---------------- W repack: fp32 [k][n] -> bf16 B-fragment order ----------------
__global__ __launch_bounds__(256) void repack_w_kernel(
    const float* __restrict__ W, u16* __restrict__ Wp) {
  int e = blockIdx.x * 256 + threadIdx.x;  // 0..16383
  int k = e >> 7, n = e & 127;
  Wp[((k >> 3) * 128 + n) * 8 + (k & 7)] = f2bf(W[e]);
}

// ---------------- GEMM body: h = x @ W (one 128-row tile) ----------------
static __device__ __forceinline__ void gemm_body(
    const float* __restrict__ x, const u16* __restrict__ Wp,
    u16* __restrict__ hb, int n_nodes, int m0, u16* xl) {
  const int t = threadIdx.x;

  const float4* x4 = (const float4*)x;
#pragma unroll
  for (int it = 0; it < 16; ++it) {
    int i = it * 256 + t;
    int r = i >> 5, c = i & 31;
    float4 v = make_float4(0.f, 0.f, 0.f, 0.f);
    int node = m0 + r;
    if (node < n_nodes) v = x4[(size_t)node * 32 + c];
    u16x4 pk = {f2bf(v.x), f2bf(v.y), f2bf(v.z), f2bf(v.w)};
    *(u16x4*)&xl[r * 136 + c * 4] = pk;
  }
  __syncthreads();

  const int w = t >> 6, l = t & 63, q = l >> 4, n15 = l & 15;

  f32x4 acc[2][8];
#pragma unroll
  for (int mt = 0; mt < 2; ++mt)
#pragma unroll
    for (int nt = 0; nt < 8; ++nt) acc[mt][nt] = (f32x4){0.f, 0.f, 0.f, 0.f};

#pragma unroll
  for (int ks = 0; ks < 4; ++ks) {
    s16x8 a0 = *(const s16x8*)&xl[(w * 32 + n15) * 136 + ks * 32 + q * 8];
    s16x8 a1 = *(const s16x8*)&xl[(w * 32 + 16 + n15) * 136 + ks * 32 + q * 8];
#pragma unroll
    for (int nt = 0; nt < 8; ++nt) {
      s16x8 b = *(const s16x8*)&Wp[(size_t)(((ks * 4 + q) * 128) + nt * 16 + n15) * 8];
      acc[0][nt] = __builtin_amdgcn_mfma_f32_16x16x32_bf16(a0, b, acc[0][nt], 0, 0, 0);
      acc[1][nt] = __builtin_amdgcn_mfma_f32_16x16x32_bf16(a1, b, acc[1][nt], 0, 0, 0);
    }
  }
  __syncthreads();

#pragma unroll
  for (int mt = 0; mt < 2; ++mt)
#pragma unroll
    for (int nt = 0; nt < 8; ++nt)
#pragma unroll
      for (int r_ = 0; r_ < 4; ++r_)
        xl[(w * 32 + mt * 16 + q * 4 + r_) * 136 + nt * 16 + n15] =
            f2bf(acc[mt][nt][r_]);
  __syncthreads();

#pragma unroll
  for (int it = 0; it < 8; ++it) {
    int chunk = it * 256 + t;
    int r = chunk >> 4, c = chunk & 15;
    int node = m0 + r;
    if (node < n_nodes)
      *(u16x8*)(hb + (size_t)node * 128 + c * 8) = *(const u16x8*)&xl[r * 136 + c * 8];
  }
}

// ---------------- part body: partition one CH-chunk of edges into row-buckets ----------------
static __device__ __forceinline__ void part_body(
    const int* __restrict__ rows, const int* __restrict__ cols,
    const float* __restrict__ vals, int* __restrict__ gcur,
    u64* __restrict__ reg, int n_edges, int nb, int base,
    int* hist, int* ofs, int* gbase, int* lcur, int* tsum, u64* srec) {
  const int t = threadIdx.x;

  for (int i = t; i < NB_MAX; i += 256) { hist[i] = 0; lcur[i] = 0; }
  __syncthreads();

  // load 16 edges/thread (stride-256 coalesced), LDS histogram
  int r[16], c[16];
  float v[16];
  bool ok[16];
#pragma unroll
  for (int i = 0; i < 16; ++i) {
    int e = base + i * 256 + t;
    ok[i] = e < n_edges;
    r[i] = ok[i] ? rows[e] : 0;
    c[i] = ok[i] ? cols[e] : 0;
    v[i] = ok[i] ? vals[e] : 0.f;
    if (ok[i]) atomicAdd(&hist[r[i] >> 7], 1);
  }
  __syncthreads();

  // exclusive scan over NB_MAX (4/thread + Hillis over 256)
  const int b0 = t * 4;
  int h0 = hist[b0], h1 = hist[b0 + 1], h2 = hist[b0 + 2], h3 = hist[b0 + 3];
  int run = h0 + h1 + h2 + h3;
  tsum[t] = run;
  // reserve global space per bucket (coalesced atomics; independent of scan)
  for (int b = t; b < nb; b += 256) {
    int hc = hist[b];
    gbase[b] = (hc > 0) ? atomicAdd(&gcur[b], hc) : 0;
  }
  __syncthreads();
  for (int off = 1; off < 256; off <<= 1) {
    int x2 = (t >= off) ? tsum[t - off] : 0;
    __syncthreads();
    tsum[t] += x2;
    __syncthreads();
  }
  int ex = tsum[t] - run;
  ofs[b0] = ex;
  ofs[b0 + 1] = ex + h0;
  ofs[b0 + 2] = ex + h0 + h1;
  ofs[b0 + 3] = ex + h0 + h1 + h2;
  __syncthreads();

  // scatter records into bucket-sorted LDS order
#pragma unroll
  for (int i = 0; i < 16; ++i) {
    if (ok[i]) {
      int bkt = r[i] >> 7;
      int pos = ofs[bkt] + atomicAdd(&lcur[bkt], 1);
      srec[pos] = ((u64)(unsigned)r[i] << 33) | ((u64)(unsigned)c[i] << 16) |
                  (u64)f2h(v[i]);
    }
  }
  __syncthreads();

  // coalesced-run write to global bucket regions
  int nvalid = n_edges - base;
  if (nvalid > CH) nvalid = CH;
  for (int i = t; i < nvalid; i += 256) {
    u64 rec = srec[i];
    int row = (int)(rec >> 33);
    int bkt = row >> 7;
    int dst = gbase[bkt] + (i - ofs[bkt]);
    if (dst < REG_CAP) reg[(size_t)bkt * REG_CAP + dst] = rec;
  }
}

// ---------------- fused GEMM + part: independent work, %3-interleaved ----------------
__global__ __launch_bounds__(256) void gemm_part_kernel(
    const float* __restrict__ x, const u16* __restrict__ Wp, u16* __restrict__ hb,
    const int* __restrict__ rows, const int* __restrict__ cols,
    const float* __restrict__ vals, int* __restrict__ gcur, u64* __restrict__ reg,
    int n_nodes, int n_edges, int nb, int gA, int gP) {
  __shared__ union {
    u16 xl[128 * 136];  // 34816 B (gemm)
    struct {            // 50176 B (part)
      int hist[NB_MAX];
      int ofs[NB_MAX];
      int gbase[NB_MAX];
      int lcur[NB_MAX];
      int tsum[256];
      u64 srec[CH];
    } p;
  } sh;

  int bid = blockIdx.x;
  bool isP;
  int id;
  if (gA == 2 * gP) {
    // interleave: every 3rd block is a part block
    int r = bid % 3, q = bid / 3;
    isP = (r == 2);
    id = isP ? q : q * 2 + r;
  } else {
    isP = bid < gP;
    id = isP ? bid : bid - gP;
  }

  if (!isP) {
    gemm_body(x, Wp, hb, n_nodes, id * 128, sh.xl);
  } else {
    part_body(rows, cols, vals, gcur, reg, n_edges, nb, id * CH,
              sh.p.hist, sh.p.ofs, sh.p.gbase, sh.p.lcur, sh.p.tsum, sh.p.srec);
  }
}

// ---------------- standalone GEMM (fallback path only) ----------------
__global__ __launch_bounds__(256) void mfma_gemm_kernel(
    const float* __restrict__ x, const u16* __restrict__ Wp,
    u16* __restrict__ hb, int n_nodes) {
  __shared__ u16 xl[128 * 136];
  gemm_body(x, Wp, hb, n_nodes, blockIdx.x * 128, xl);
}

// ---------------- pass 2: streaming double-buffered gather-accumulate ----------------
// Wave w owns local rows [8w, 8w+8) = contiguous srt segment; stream it with
// ping-pong 8-batches so ~16 gathers stay in flight continuously.
static __device__ __forceinline__ void gload8(
    const u64* __restrict__ srt, int p, int s1, const unsigned* __restrict__ h32,
    int lane, unsigned mv[8], unsigned uu[8]) {
#pragma unroll
  for (int j = 0; j < 8; ++j) {
    int idx = p + j;
    bool vb = idx < s1;
    idx = vb ? idx : s1 - 1;
    u64 rec = srt[idx];  // wave-uniform address -> broadcast
    int col = (int)((rec >> 16) & 0x1FFFF);
    unsigned val = vb ? (unsigned)(rec & 0xFFFF) : 0u;  // fp16 +0 -> no-op
    mv[j] = ((unsigned)((rec >> 33) & (RB - 1)) << 16) | val;
    uu[j] = h32[((unsigned)col << 6) | lane];
  }
}
static __device__ __forceinline__ void gcons8(
    const unsigned mv[8], const unsigned uu[8], int& cur, float2& acc,
    float2* __restrict__ out2, int row0, int lane) {
#pragma unroll
  for (int j = 0; j < 8; ++j) {
    int lr = (int)(mv[j] >> 16);
    if (lr != cur) {  // wave-uniform (mv from broadcast LDS read)
      out2[(size_t)(row0 + cur) * 64 + lane] = acc;
      acc = make_float2(0.f, 0.f);
      cur = lr;
    }
    float vv = h2f((u16)(mv[j] & 0xFFFF));
    acc.x += vv * bf_lo(uu[j]);
    acc.y += vv * bf_hi(uu[j]);
  }
}

__global__ __launch_bounds__(1024, 8) void bucket_accum_kernel(
    const u16* __restrict__ hb, const u64* __restrict__ reg,
    const int* __restrict__ gcur, float* __restrict__ out, int n_nodes) {
  __shared__ int hist[RB];
  __shared__ int ofs[RB];
  __shared__ int lcur[RB];
  __shared__ u64 srt[REG_CAP];

  const int t = threadIdx.x;
  const int b = blockIdx.x;
  const int row0 = b * RB;

  int n_e = gcur[b];
  if (n_e > REG_CAP) n_e = REG_CAP;

  if (t < RB) { hist[t] = 0; lcur[t] = 0; }
  __syncthreads();

  // load region once (coalesced, LLC-resident), histogram by local row
  u64 rr[3];
  int rl[3];
  bool ok[3];
#pragma unroll
  for (int i = 0; i < 3; ++i) {
    int j = i * 1024 + t;
    ok[i] = j < n_e;
    rr[i] = ok[i] ? reg[(size_t)b * REG_CAP + j] : 0;
    rl[i] = (int)(rr[i] >> 33) & (RB - 1);
    if (ok[i]) atomicAdd(&hist[rl[i]], 1);
  }
  __syncthreads();

  // exclusive scan of RB=128 entries by wave 0: 2 entries/lane shuffle scan
  if (t < 64) {
    int h0 = hist[2 * t], h1 = hist[2 * t + 1];
    int s = h0 + h1;
    int v = s;
#pragma unroll
    for (int off = 1; off < 64; off <<= 1) {
      int u = __shfl_up(v, off, 64);
      if (t >= off) v += u;
    }
    int ex = v - s;  // exclusive prefix of pair-sums
    ofs[2 * t] = ex;
    ofs[2 * t + 1] = ex + h0;
  }
  __syncthreads();

  // scatter records into row-sorted LDS order
#pragma unroll
  for (int i = 0; i < 3; ++i) {
    if (ok[i]) {
      int pos = ofs[rl[i]] + atomicAdd(&lcur[rl[i]], 1);
      srt[pos] = rr[i];
    }
  }
  __syncthreads();

  const int lane = t & 63;
  const int w = t >> 6;  // 0..15
  const unsigned* h32 = (const unsigned*)hb;
  float2* out2 = (float2*)out;

  const int r0 = w * 8;  // this wave's local rows r0..r0+7

  // zero-fill rows with no edges (streaming never flushes them)
#pragma unroll
  for (int k = 0; k < 8; ++k) {
    int rli = r0 + k;
    int gr = row0 + rli;
    if (gr < n_nodes && hist[rli] == 0)
      out2[(size_t)gr * 64 + lane] = make_float2(0.f, 0.f);
  }

  int s0 = ofs[r0];
  int s1 = ofs[r0 + 7] + hist[r0 + 7];
  if (s1 > s0) {
    float2 acc = make_float2(0.f, 0.f);
    int cur = (int)(srt[s0] >> 33) & (RB - 1);
    unsigned mvA[8], uuA[8], mvB[8], uuB[8];
    int nbt = (s1 - s0 + 7) >> 3;
    int p = s0;
    gload8(srt, p, s1, h32, lane, mvA, uuA);
    p += 8;
    for (int bi = 1; bi < nbt; ++bi) {
      if (bi & 1) {
        gload8(srt, p, s1, h32, lane, mvB, uuB);  // B in flight...
        gcons8(mvA, uuA, cur, acc, out2, row0, lane);  // ...while consuming A
      } else {
        gload8(srt, p, s1, h32, lane, mvA, uuA);
        gcons8(mvB, uuB, cur, acc, out2, row0, lane);
      }
      p += 8;
    }
    if (nbt & 1) gcons8(mvA, uuA, cur, acc, out2, row0, lane);
    else gcons8(mvB, uuB, cur, acc, out2, row0, lane);
    out2[(size_t)(row0 + cur) * 64 + lane] = acc;  // final flush
  }
}

// ---------------- fallback (atomic scatter on bf16 h) ----------------
__global__ __launch_bounds__(256) void scatter_kernel(
    const u16* __restrict__ hb, const float* __restrict__ vals,
    const int* __restrict__ rows, const int* __restrict__ cols,
    float* __restrict__ out, int n_edges) {
  const int lane = threadIdx.x & 63;
  const int wid = (blockIdx.x * blockDim.x + threadIdx.x) >> 6;
  const int nwaves = (gridDim.x * blockDim.x) >> 6;
  const unsigned* h32 = (const unsigned*)hb;
  for (int e = wid; e < n_edges; e += nwaves) {
    int r = rows[e];
    int c = cols[e];
    float v = vals[e];
    unsigned u = h32[(size_t)c * 64 + lane];
    float* op = out + (size_t)r * DIM + 2 * lane;
    atomicAdd(op, v * bf_lo(u));
    atomicAdd(op + 1, v * bf_hi(u));
  }
}

extern "C" void kernel_launch(void* const* d_in, const int* in_sizes, int n_in,
                              void* d_out, int out_size, void* d_ws, size_t ws_size,
                              hipStream_t stream) {
  const float* x = (const float*)d_in[0];
  const float* W = (const float*)d_in[1];
  const float* edge_vals = (const float*)d_in[2];
  const int* edge_rows = (const int*)d_in[3];
  const int* edge_cols = (const int*)d_in[4];
  float* out = (float*)d_out;

  const int n_nodes = in_sizes[0] / DIM;
  const int n_edges = in_sizes[2];
  const int nb = (n_nodes + RB - 1) / RB;

  // ws layout (16B-aligned chunks)
  char* p = (char*)d_ws;
  u16* hb = (u16*)p;   p += (((size_t)n_nodes * DIM * 2 + 15) / 16) * 16;  // 25.6 MB
  u16* Wp = (u16*)p;   p += (size_t)DIM * DIM * 2;                         // 32 KB
  int* gcur = (int*)p; p += (((size_t)nb * 4 + 15) / 16) * 16;             // ~3 KB
  u64* reg = (u64*)p;  p += (size_t)nb * REG_CAP * 8;                      // ~16 MB
  const size_t need = (size_t)(p - (char*)d_ws);

  repack_w_kernel<<<64, 256, 0, stream>>>(W, Wp);

  if (ws_size < need || nb > NB_MAX) {
    mfma_gemm_kernel<<<(n_nodes + 127) / 128, 256, 0, stream>>>(x, Wp, hb, n_nodes);
    hipMemsetAsync(d_out, 0, (size_t)out_size * sizeof(float), stream);
    scatter_kernel<<<2048, 256, 0, stream>>>(hb, edge_vals, edge_rows, edge_cols,
                                             out, n_edges);
    return;
  }

  hipMemsetAsync(gcur, 0, (size_t)nb * sizeof(int), stream);

  const int gA = (n_nodes + 127) / 128;
  const int gP = (n_edges + CH - 1) / CH;
  gemm_part_kernel<<<gA + gP, 256, 0, stream>>>(x, Wp, hb, edge_rows, edge_cols,
                                                edge_vals, gcur, reg, n_nodes,
                                                n_edges, nb, gA, gP);

  bucket_accum_kernel<<<nb, 1024, 0, stream>>>(hb, reg, gcur, out, n_nodes);
}

// Round 4
// 239.571 us; speedup vs baseline: 1.6204x; 1.6204x over previous
//
#include <hip/hip_runtime.h>
#include <hip/hip_bf16.h>
#include <hip/hip_fp16.h>

// GNN layer: out = segment_sum(edge_vals * h[edge_cols], edge_rows), h = x @ W
// N=100000 nodes, E=1.6M edges, D=128.
//
// R9: R8's ping-pong spilled (launch_bounds(1024,8) -> 32 VGPR budget-forced,
// mv/uu arrays went to scratch: WRITE_SIZE 50->548MB, dur 73->265us). The
// pipeline never existed in the emitted code. Retry with a register-lean
// version: only the gathered uu[8] double-buffer in registers (16 VGPR);
// record metadata re-read from LDS at consume (wave-uniform broadcast).
// __launch_bounds__(1024,4) -> 128-VGPR budget, no spill; expected ~44 VGPR
// still allows 2 blocks/CU (slot-capped 32 waves). Keep R8's gemm+part
// fusion (saved ~28us on the non-bucket portion).

#define DIM 128
#define RB 128        // rows per bucket (pass-1 partition granularity)
#define NB_MAX 1024   // max buckets supported by pass1 LDS arrays
#define CH 4096       // edges per pass1 block
#define REG_CAP 2560  // records per bucket region (mean 2048, +11 sigma)

typedef short s16x8 __attribute__((ext_vector_type(8)));
typedef float f32x4 __attribute__((ext_vector_type(4)));
typedef unsigned short u16;
typedef unsigned long long u64;
typedef u16 u16x4 __attribute__((ext_vector_type(4)));
typedef u16 u16x8 __attribute__((ext_vector_type(8)));

static __device__ __forceinline__ u16 f2bf(float f) {
  union { float f; unsigned u; } a; a.f = f;
  return (u16)((a.u + 0x7fffu + ((a.u >> 16) & 1u)) >> 16);
}
static __device__ __forceinline__ float bf_lo(unsigned u) {
  union { unsigned u; float f; } a; a.u = u << 16; return a.f;
}
static __device__ __forceinline__ float bf_hi(unsigned u) {
  union { unsigned u; float f; } a; a.u = u & 0xffff0000u; return a.f;
}
static __device__ __forceinline__ u16 f2h(float f) {
  return __half_as_ushort(__float2half(f));
}
static __device__ __forceinline__ float h2f(u16 h) {
  return __half2float(__ushort_as_half(h));
}

// ---------------- W repack: fp32 [k][n] -> bf16 B-fragment order ----------------
__global__ __launch_bounds__(256) void repack_w_kernel(
    const float* __restrict__ W, u16* __restrict__ Wp) {
  int e = blockIdx.x * 256 + threadIdx.x;  // 0..16383
  int k = e >> 7, n = e & 127;
  Wp[((k >> 3) * 128 + n) * 8 + (k & 7)] = f2bf(W[e]);
}

// ---------------- GEMM body: h = x @ W (one 128-row tile) ----------------
static __device__ __forceinline__ void gemm_body(
    const float* __restrict__ x, const u16* __restrict__ Wp,
    u16* __restrict__ hb, int n_nodes, int m0, u16* xl) {
  const int t = threadIdx.x;

  const float4* x4 = (const float4*)x;
#pragma unroll
  for (int it = 0; it < 16; ++it) {
    int i = it * 256 + t;
    int r = i >> 5, c = i & 31;
    float4 v = make_float4(0.f, 0.f, 0.f, 0.f);
    int node = m0 + r;
    if (node < n_nodes) v = x4[(size_t)node * 32 + c];
    u16x4 pk = {f2bf(v.x), f2bf(v.y), f2bf(v.z), f2bf(v.w)};
    *(u16x4*)&xl[r * 136 + c * 4] = pk;
  }
  __syncthreads();

  const int w = t >> 6, l = t & 63, q = l >> 4, n15 = l & 15;

  f32x4 acc[2][8];
#pragma unroll
  for (int mt = 0; mt < 2; ++mt)
#pragma unroll
    for (int nt = 0; nt < 8; ++nt) acc[mt][nt] = (f32x4){0.f, 0.f, 0.f, 0.f};

#pragma unroll
  for (int ks = 0; ks < 4; ++ks) {
    s16x8 a0 = *(const s16x8*)&xl[(w * 32 + n15) * 136 + ks * 32 + q * 8];
    s16x8 a1 = *(const s16x8*)&xl[(w * 32 + 16 + n15) * 136 + ks * 32 + q * 8];
#pragma unroll
    for (int nt = 0; nt < 8; ++nt) {
      s16x8 b = *(const s16x8*)&Wp[(size_t)(((ks * 4 + q) * 128) + nt * 16 + n15) * 8];
      acc[0][nt] = __builtin_amdgcn_mfma_f32_16x16x32_bf16(a0, b, acc[0][nt], 0, 0, 0);
      acc[1][nt] = __builtin_amdgcn_mfma_f32_16x16x32_bf16(a1, b, acc[1][nt], 0, 0, 0);
    }
  }
  __syncthreads();

#pragma unroll
  for (int mt = 0; mt < 2; ++mt)
#pragma unroll
    for (int nt = 0; nt < 8; ++nt)
#pragma unroll
      for (int r_ = 0; r_ < 4; ++r_)
        xl[(w * 32 + mt * 16 + q * 4 + r_) * 136 + nt * 16 + n15] =
            f2bf(acc[mt][nt][r_]);
  __syncthreads();

#pragma unroll
  for (int it = 0; it < 8; ++it) {
    int chunk = it * 256 + t;
    int r = chunk >> 4, c = chunk & 15;
    int node = m0 + r;
    if (node < n_nodes)
      *(u16x8*)(hb + (size_t)node * 128 + c * 8) = *(const u16x8*)&xl[r * 136 + c * 8];
  }
}

// ---------------- part body: partition one CH-chunk of edges into row-buckets ----------------
static __device__ __forceinline__ void part_body(
    const int* __restrict__ rows, const int* __restrict__ cols,
    const float* __restrict__ vals, int* __restrict__ gcur,
    u64* __restrict__ reg, int n_edges, int nb, int base,
    int* hist, int* ofs, int* gbase, int* lcur, int* tsum, u64* srec) {
  const int t = threadIdx.x;

  for (int i = t; i < NB_MAX; i += 256) { hist[i] = 0; lcur[i] = 0; }
  __syncthreads();

  // load 16 edges/thread (stride-256 coalesced), LDS histogram
  int r[16], c[16];
  float v[16];
  bool ok[16];
#pragma unroll
  for (int i = 0; i < 16; ++i) {
    int e = base + i * 256 + t;
    ok[i] = e < n_edges;
    r[i] = ok[i] ? rows[e] : 0;
    c[i] = ok[i] ? cols[e] : 0;
    v[i] = ok[i] ? vals[e] : 0.f;
    if (ok[i]) atomicAdd(&hist[r[i] >> 7], 1);
  }
  __syncthreads();

  // exclusive scan over NB_MAX (4/thread + Hillis over 256)
  const int b0 = t * 4;
  int h0 = hist[b0], h1 = hist[b0 + 1], h2 = hist[b0 + 2], h3 = hist[b0 + 3];
  int run = h0 + h1 + h2 + h3;
  tsum[t] = run;
  // reserve global space per bucket (coalesced atomics; independent of scan)
  for (int b = t; b < nb; b += 256) {
    int hc = hist[b];
    gbase[b] = (hc > 0) ? atomicAdd(&gcur[b], hc) : 0;
  }
  __syncthreads();
  for (int off = 1; off < 256; off <<= 1) {
    int x2 = (t >= off) ? tsum[t - off] : 0;
    __syncthreads();
    tsum[t] += x2;
    __syncthreads();
  }
  int ex = tsum[t] - run;
  ofs[b0] = ex;
  ofs[b0 + 1] = ex + h0;
  ofs[b0 + 2] = ex + h0 + h1;
  ofs[b0 + 3] = ex + h0 + h1 + h2;
  __syncthreads();

  // scatter records into bucket-sorted LDS order
#pragma unroll
  for (int i = 0; i < 16; ++i) {
    if (ok[i]) {
      int bkt = r[i] >> 7;
      int pos = ofs[bkt] + atomicAdd(&lcur[bkt], 1);
      srec[pos] = ((u64)(unsigned)r[i] << 33) | ((u64)(unsigned)c[i] << 16) |
                  (u64)f2h(v[i]);
    }
  }
  __syncthreads();

  // coalesced-run write to global bucket regions
  int nvalid = n_edges - base;
  if (nvalid > CH) nvalid = CH;
  for (int i = t; i < nvalid; i += 256) {
    u64 rec = srec[i];
    int row = (int)(rec >> 33);
    int bkt = row >> 7;
    int dst = gbase[bkt] + (i - ofs[bkt]);
    if (dst < REG_CAP) reg[(size_t)bkt * REG_CAP + dst] = rec;
  }
}

// ---------------- fused GEMM + part: independent work, %3-interleaved ----------------
__global__ __launch_bounds__(256) void gemm_part_kernel(
    const float* __restrict__ x, const u16* __restrict__ Wp, u16* __restrict__ hb,
    const int* __restrict__ rows, const int* __restrict__ cols,
    const float* __restrict__ vals, int* __restrict__ gcur, u64* __restrict__ reg,
    int n_nodes, int n_edges, int nb, int gA, int gP) {
  __shared__ union {
    u16 xl[128 * 136];  // 34816 B (gemm)
    struct {            // 50176 B (part)
      int hist[NB_MAX];
      int ofs[NB_MAX];
      int gbase[NB_MAX];
      int lcur[NB_MAX];
      int tsum[256];
      u64 srec[CH];
    } p;
  } sh;

  int bid = blockIdx.x;
  bool isP;
  int id;
  if (gA == 2 * gP) {
    // interleave: every 3rd block is a part block
    int r = bid % 3, q = bid / 3;
    isP = (r == 2);
    id = isP ? q : q * 2 + r;
  } else {
    isP = bid < gP;
    id = isP ? bid : bid - gP;
  }

  if (!isP) {
    gemm_body(x, Wp, hb, n_nodes, id * 128, sh.xl);
  } else {
    part_body(rows, cols, vals, gcur, reg, n_edges, nb, id * CH,
              sh.p.hist, sh.p.ofs, sh.p.gbase, sh.p.lcur, sh.p.tsum, sh.p.srec);
  }
}

// ---------------- standalone GEMM (fallback path only) ----------------
__global__ __launch_bounds__(256) void mfma_gemm_kernel(
    const float* __restrict__ x, const u16* __restrict__ Wp,
    u16* __restrict__ hb, int n_nodes) {
  __shared__ u16 xl[128 * 136];
  gemm_body(x, Wp, hb, n_nodes, blockIdx.x * 128, xl);
}

// ---------------- pass 2: streaming gather with register-lean double-buffer ----------------
// Issue phase: compute addrs from srt (LDS, wave-uniform) and gather h into
// uu[8] regs. Consume phase: re-read srt from LDS for row/val (broadcast,
// ~free) and FMA. Only the two uu[8] buffers live across phases -> ~16 VGPR
// of pipeline state, no spill risk.
static __device__ __forceinline__ void issue8(
    const u64* __restrict__ srt, int p, int s1,
    const unsigned* __restrict__ h32, int lane, unsigned uu[8]) {
#pragma unroll
  for (int j = 0; j < 8; ++j) {
    int idx = p + j;
    idx = idx < s1 ? idx : s1 - 1;  // clamp: duplicate gather, masked at consume
    u64 rec = srt[idx];             // wave-uniform -> broadcast
    int col = (int)((rec >> 16) & 0x1FFFF);
    uu[j] = h32[((size_t)col << 6) | lane];
  }
}
static __device__ __forceinline__ void consume8(
    const u64* __restrict__ srt, int p, int s1, const unsigned uu[8],
    int& cur, float2& acc, float2* __restrict__ out2, int row0, int lane) {
#pragma unroll
  for (int j = 0; j < 8; ++j) {
    int idx = p + j;
    if (idx < s1) {  // wave-uniform predicate
      u64 rec = srt[idx];
      int lr = (int)(rec >> 33) & (RB - 1);
      if (lr != cur) {  // wave-uniform (srt read is uniform)
        out2[(size_t)(row0 + cur) * 64 + lane] = acc;
        acc = make_float2(0.f, 0.f);
        cur = lr;
      }
      float vv = h2f((u16)(rec & 0xFFFF));
      acc.x += vv * bf_lo(uu[j]);
      acc.y += vv * bf_hi(uu[j]);
    }
  }
}

__global__ __launch_bounds__(1024, 4) void bucket_accum_kernel(
    const u16* __restrict__ hb, const u64* __restrict__ reg,
    const int* __restrict__ gcur, float* __restrict__ out, int n_nodes) {
  __shared__ int hist[RB];
  __shared__ int ofs[RB];
  __shared__ int lcur[RB];
  __shared__ u64 srt[REG_CAP];

  const int t = threadIdx.x;
  const int b = blockIdx.x;
  const int row0 = b * RB;

  int n_e = gcur[b];
  if (n_e > REG_CAP) n_e = REG_CAP;

  if (t < RB) { hist[t] = 0; lcur[t] = 0; }
  __syncthreads();

  // load region once (coalesced, LLC-resident), histogram by local row
  u64 rr[3];
  int rl[3];
  bool ok[3];
#pragma unroll
  for (int i = 0; i < 3; ++i) {
    int j = i * 1024 + t;
    ok[i] = j < n_e;
    rr[i] = ok[i] ? reg[(size_t)b * REG_CAP + j] : 0;
    rl[i] = (int)(rr[i] >> 33) & (RB - 1);
    if (ok[i]) atomicAdd(&hist[rl[i]], 1);
  }
  __syncthreads();

  // exclusive scan of RB=128 entries by wave 0: 2 entries/lane shuffle scan
  if (t < 64) {
    int h0 = hist[2 * t], h1 = hist[2 * t + 1];
    int s = h0 + h1;
    int v = s;
#pragma unroll
    for (int off = 1; off < 64; off <<= 1) {
      int u = __shfl_up(v, off, 64);
      if (t >= off) v += u;
    }
    int ex = v - s;  // exclusive prefix of pair-sums
    ofs[2 * t] = ex;
    ofs[2 * t + 1] = ex + h0;
  }
  __syncthreads();

  // scatter records into row-sorted LDS order
#pragma unroll
  for (int i = 0; i < 3; ++i) {
    if (ok[i]) {
      int pos = ofs[rl[i]] + atomicAdd(&lcur[rl[i]], 1);
      srt[pos] = rr[i];
    }
  }
  __syncthreads();

  const int lane = t & 63;
  const int w = t >> 6;  // 0..15
  const unsigned* h32 = (const unsigned*)hb;
  float2* out2 = (float2*)out;

  const int r0 = w * 8;  // this wave's local rows r0..r0+7

  // zero-fill rows with no edges (streaming never flushes them)
#pragma unroll
  for (int k = 0; k < 8; ++k) {
    int rli = r0 + k;
    int gr = row0 + rli;
    if (gr < n_nodes && hist[rli] == 0)
      out2[(size_t)gr * 64 + lane] = make_float2(0.f, 0.f);
  }

  int s0 = ofs[r0];
  int s1 = ofs[r0 + 7] + hist[r0 + 7];
  if (s1 > s0) {
    float2 acc = make_float2(0.f, 0.f);
    int cur = (int)(srt[s0] >> 33) & (RB - 1);
    unsigned uuA[8], uuB[8];
    int nbt = (s1 - s0 + 7) >> 3;
    issue8(srt, s0, s1, h32, lane, uuA);
    for (int bi = 1; bi < nbt; ++bi) {
      int pl = s0 + bi * 8;
      int pc = pl - 8;
      if (bi & 1) {
        issue8(srt, pl, s1, h32, lane, uuB);   // B's gathers in flight...
        consume8(srt, pc, s1, uuA, cur, acc, out2, row0, lane);  // ...consume A
      } else {
        issue8(srt, pl, s1, h32, lane, uuA);
        consume8(srt, pc, s1, uuB, cur, acc, out2, row0, lane);
      }
    }
    int pc = s0 + (nbt - 1) * 8;
    if (nbt & 1) consume8(srt, pc, s1, uuA, cur, acc, out2, row0, lane);
    else consume8(srt, pc, s1, uuB, cur, acc, out2, row0, lane);
    out2[(size_t)(row0 + cur) * 64 + lane] = acc;  // final flush
  }
}

// ---------------- fallback (atomic scatter on bf16 h) ----------------
__global__ __launch_bounds__(256) void scatter_kernel(
    const u16* __restrict__ hb, const float* __restrict__ vals,
    const int* __restrict__ rows, const int* __restrict__ cols,
    float* __restrict__ out, int n_edges) {
  const int lane = threadIdx.x & 63;
  const int wid = (blockIdx.x * blockDim.x + threadIdx.x) >> 6;
  const int nwaves = (gridDim.x * blockDim.x) >> 6;
  const unsigned* h32 = (const unsigned*)hb;
  for (int e = wid; e < n_edges; e += nwaves) {
    int r = rows[e];
    int c = cols[e];
    float v = vals[e];
    unsigned u = h32[(size_t)c * 64 + lane];
    float* op = out + (size_t)r * DIM + 2 * lane;
    atomicAdd(op, v * bf_lo(u));
    atomicAdd(op + 1, v * bf_hi(u));
  }
}

extern "C" void kernel_launch(void* const* d_in, const int* in_sizes, int n_in,
                              void* d_out, int out_size, void* d_ws, size_t ws_size,
                              hipStream_t stream) {
  const float* x = (const float*)d_in[0];
  const float* W = (const float*)d_in[1];
  const float* edge_vals = (const float*)d_in[2];
  const int* edge_rows = (const int*)d_in[3];
  const int* edge_cols = (const int*)d_in[4];
  float* out = (float*)d_out;

  const int n_nodes = in_sizes[0] / DIM;
  const int n_edges = in_sizes[2];
  const int nb = (n_nodes + RB - 1) / RB;

  // ws layout (16B-aligned chunks)
  char* p = (char*)d_ws;
  u16* hb = (u16*)p;   p += (((size_t)n_nodes * DIM * 2 + 15) / 16) * 16;  // 25.6 MB
  u16* Wp = (u16*)p;   p += (size_t)DIM * DIM * 2;                         // 32 KB
  int* gcur = (int*)p; p += (((size_t)nb * 4 + 15) / 16) * 16;             // ~3 KB
  u64* reg = (u64*)p;  p += (size_t)nb * REG_CAP * 8;                      // ~16 MB
  const size_t need = (size_t)(p - (char*)d_ws);

  repack_w_kernel<<<64, 256, 0, stream>>>(W, Wp);

  if (ws_size < need || nb > NB_MAX) {
    mfma_gemm_kernel<<<(n_nodes + 127) / 128, 256, 0, stream>>>(x, Wp, hb, n_nodes);
    hipMemsetAsync(d_out, 0, (size_t)out_size * sizeof(float), stream);
    scatter_kernel<<<2048, 256, 0, stream>>>(hb, edge_vals, edge_rows, edge_cols,
                                             out, n_edges);
    return;
  }

  hipMemsetAsync(gcur, 0, (size_t)nb * sizeof(int), stream);

  const int gA = (n_nodes + 127) / 128;
  const int gP = (n_edges + CH - 1) / CH;
  gemm_part_kernel<<<gA + gP, 256, 0, stream>>>(x, Wp, hb, edge_rows, edge_cols,
                                                edge_vals, gcur, reg, n_nodes,
                                                n_edges, nb, gA, gP);

  bucket_accum_kernel<<<nb, 1024, 0, stream>>>(hb, reg, gcur, out, n_nodes);
}

// Round 5
// 223.895 us; speedup vs baseline: 1.7338x; 1.0700x over previous
//
#include <hip/hip_runtime.h>
#include <hip/hip_bf16.h>
#include <hip/hip_fp16.h>

// GNN layer: out = segment_sum(edge_vals * h[edge_cols], edge_rows), h = x @ W
// N=100000 nodes, E=1.6M edges, D=128.
//
// R10: R7's VGPR_Count=20 proves the compiler serialized the "8-deep" gather
// (can't hold 8 uu + 8 vv in 20 regs) -> the MLP hypothesis was never actually
// tested; R9's LDS-re-read variant just added decode work (VALU 52%, 85us).
// New pass 2: QUARTER-WAVE gathers. Each 16-lane quarter owns 2 rows and
// reads a full 256B h-row as dwordx4 (16 lanes x 16B). One VMEM instruction
// = 4 records (one per quarter); unroll 4 = 16 records in flight per wave
// (vs ~2-4 before), VMEM instruction count / loop overhead 4x lower.
// Metadata packed in mv[4] regs (no LDS re-read). ~46 VGPR by construction;
// launch_bounds(1024,6) = 85-VGPR budget (no spill squeeze), runtime still
// 2 blocks/CU. GEMM+part fusion kept.

#define DIM 128
#define RB 128        // rows per bucket (pass-1 partition granularity)
#define NB_MAX 1024   // max buckets supported by pass1 LDS arrays
#define CH 4096       // edges per pass1 block
#define REG_CAP 2560  // records per bucket region (mean 2048, +11 sigma)

typedef short s16x8 __attribute__((ext_vector_type(8)));
typedef float f32x4 __attribute__((ext_vector_type(4)));
typedef unsigned short u16;
typedef unsigned long long u64;
typedef u16 u16x4 __attribute__((ext_vector_type(4)));
typedef u16 u16x8 __attribute__((ext_vector_type(8)));

static __device__ __forceinline__ u16 f2bf(float f) {
  union { float f; unsigned u; } a; a.f = f;
  return (u16)((a.u + 0x7fffu + ((a.u >> 16) & 1u)) >> 16);
}
static __device__ __forceinline__ float bf_lo(unsigned u) {
  union { unsigned u; float f; } a; a.u = u << 16; return a.f;
}
static __device__ __forceinline__ float bf_hi(unsigned u) {
  union { unsigned u; float f; } a; a.u = u & 0xffff0000u; return a.f;
}
static __device__ __forceinline__ u16 f2h(float f) {
  return __half_as_ushort(__float2half(f));
}
static __device__ __forceinline__ float h2f(u16 h) {
  return __half2float(__ushort_as_half(h));
}

// ---------------- W repack: fp32 [k][n] -> bf16 B-fragment order ----------------
__global__ __launch_bounds__(256) void repack_w_kernel(
    const float* __restrict__ W, u16* __restrict__ Wp) {
  int e = blockIdx.x * 256 + threadIdx.x;  // 0..16383
  int k = e >> 7, n = e & 127;
  Wp[((k >> 3) * 128 + n) * 8 + (k & 7)] = f2bf(W[e]);
}

// ---------------- GEMM body: h = x @ W (one 128-row tile) ----------------
static __device__ __forceinline__ void gemm_body(
    const float* __restrict__ x, const u16* __restrict__ Wp,
    u16* __restrict__ hb, int n_nodes, int m0, u16* xl) {
  const int t = threadIdx.x;

  const float4* x4 = (const float4*)x;
#pragma unroll
  for (int it = 0; it < 16; ++it) {
    int i = it * 256 + t;
    int r = i >> 5, c = i & 31;
    float4 v = make_float4(0.f, 0.f, 0.f, 0.f);
    int node = m0 + r;
    if (node < n_nodes) v = x4[(size_t)node * 32 + c];
    u16x4 pk = {f2bf(v.x), f2bf(v.y), f2bf(v.z), f2bf(v.w)};
    *(u16x4*)&xl[r * 136 + c * 4] = pk;
  }
  __syncthreads();

  const int w = t >> 6, l = t & 63, q = l >> 4, n15 = l & 15;

  f32x4 acc[2][8];
#pragma unroll
  for (int mt = 0; mt < 2; ++mt)
#pragma unroll
    for (int nt = 0; nt < 8; ++nt) acc[mt][nt] = (f32x4){0.f, 0.f, 0.f, 0.f};

#pragma unroll
  for (int ks = 0; ks < 4; ++ks) {
    s16x8 a0 = *(const s16x8*)&xl[(w * 32 + n15) * 136 + ks * 32 + q * 8];
    s16x8 a1 = *(const s16x8*)&xl[(w * 32 + 16 + n15) * 136 + ks * 32 + q * 8];
#pragma unroll
    for (int nt = 0; nt < 8; ++nt) {
      s16x8 b = *(const s16x8*)&Wp[(size_t)(((ks * 4 + q) * 128) + nt * 16 + n15) * 8];
      acc[0][nt] = __builtin_amdgcn_mfma_f32_16x16x32_bf16(a0, b, acc[0][nt], 0, 0, 0);
      acc[1][nt] = __builtin_amdgcn_mfma_f32_16x16x32_bf16(a1, b, acc[1][nt], 0, 0, 0);
    }
  }
  __syncthreads();

#pragma unroll
  for (int mt = 0; mt < 2; ++mt)
#pragma unroll
    for (int nt = 0; nt < 8; ++nt)
#pragma unroll
      for (int r_ = 0; r_ < 4; ++r_)
        xl[(w * 32 + mt * 16 + q * 4 + r_) * 136 + nt * 16 + n15] =
            f2bf(acc[mt][nt][r_]);
  __syncthreads();

#pragma unroll
  for (int it = 0; it < 8; ++it) {
    int chunk = it * 256 + t;
    int r = chunk >> 4, c = chunk & 15;
    int node = m0 + r;
    if (node < n_nodes)
      *(u16x8*)(hb + (size_t)node * 128 + c * 8) = *(const u16x8*)&xl[r * 136 + c * 8];
  }
}

// ---------------- part body: partition one CH-chunk of edges into row-buckets ----------------
static __device__ __forceinline__ void part_body(
    const int* __restrict__ rows, const int* __restrict__ cols,
    const float* __restrict__ vals, int* __restrict__ gcur,
    u64* __restrict__ reg, int n_edges, int nb, int base,
    int* hist, int* ofs, int* gbase, int* lcur, int* tsum, u64* srec) {
  const int t = threadIdx.x;

  for (int i = t; i < NB_MAX; i += 256) { hist[i] = 0; lcur[i] = 0; }
  __syncthreads();

  // load 16 edges/thread (stride-256 coalesced), LDS histogram
  int r[16], c[16];
  float v[16];
  bool ok[16];
#pragma unroll
  for (int i = 0; i < 16; ++i) {
    int e = base + i * 256 + t;
    ok[i] = e < n_edges;
    r[i] = ok[i] ? rows[e] : 0;
    c[i] = ok[i] ? cols[e] : 0;
    v[i] = ok[i] ? vals[e] : 0.f;
    if (ok[i]) atomicAdd(&hist[r[i] >> 7], 1);
  }
  __syncthreads();

  // exclusive scan over NB_MAX (4/thread + Hillis over 256)
  const int b0 = t * 4;
  int h0 = hist[b0], h1 = hist[b0 + 1], h2 = hist[b0 + 2], h3 = hist[b0 + 3];
  int run = h0 + h1 + h2 + h3;
  tsum[t] = run;
  // reserve global space per bucket (coalesced atomics; independent of scan)
  for (int b = t; b < nb; b += 256) {
    int hc = hist[b];
    gbase[b] = (hc > 0) ? atomicAdd(&gcur[b], hc) : 0;
  }
  __syncthreads();
  for (int off = 1; off < 256; off <<= 1) {
    int x2 = (t >= off) ? tsum[t - off] : 0;
    __syncthreads();
    tsum[t] += x2;
    __syncthreads();
  }
  int ex = tsum[t] - run;
  ofs[b0] = ex;
  ofs[b0 + 1] = ex + h0;
  ofs[b0 + 2] = ex + h0 + h1;
  ofs[b0 + 3] = ex + h0 + h1 + h2;
  __syncthreads();

  // scatter records into bucket-sorted LDS order
#pragma unroll
  for (int i = 0; i < 16; ++i) {
    if (ok[i]) {
      int bkt = r[i] >> 7;
      int pos = ofs[bkt] + atomicAdd(&lcur[bkt], 1);
      srec[pos] = ((u64)(unsigned)r[i] << 33) | ((u64)(unsigned)c[i] << 16) |
                  (u64)f2h(v[i]);
    }
  }
  __syncthreads();

  // coalesced-run write to global bucket regions
  int nvalid = n_edges - base;
  if (nvalid > CH) nvalid = CH;
  for (int i = t; i < nvalid; i += 256) {
    u64 rec = srec[i];
    int row = (int)(rec >> 33);
    int bkt = row >> 7;
    int dst = gbase[bkt] + (i - ofs[bkt]);
    if (dst < REG_CAP) reg[(size_t)bkt * REG_CAP + dst] = rec;
  }
}

// ---------------- fused GEMM + part: independent work, %3-interleaved ----------------
__global__ __launch_bounds__(256) void gemm_part_kernel(
    const float* __restrict__ x, const u16* __restrict__ Wp, u16* __restrict__ hb,
    const int* __restrict__ rows, const int* __restrict__ cols,
    const float* __restrict__ vals, int* __restrict__ gcur, u64* __restrict__ reg,
    int n_nodes, int n_edges, int nb, int gA, int gP) {
  __shared__ union {
    u16 xl[128 * 136];  // 34816 B (gemm)
    struct {            // 50176 B (part)
      int hist[NB_MAX];
      int ofs[NB_MAX];
      int gbase[NB_MAX];
      int lcur[NB_MAX];
      int tsum[256];
      u64 srec[CH];
    } p;
  } sh;

  int bid = blockIdx.x;
  bool isP;
  int id;
  if (gA == 2 * gP) {
    // interleave: every 3rd block is a part block
    int r = bid % 3, q = bid / 3;
    isP = (r == 2);
    id = isP ? q : q * 2 + r;
  } else {
    isP = bid < gP;
    id = isP ? bid : bid - gP;
  }

  if (!isP) {
    gemm_body(x, Wp, hb, n_nodes, id * 128, sh.xl);
  } else {
    part_body(rows, cols, vals, gcur, reg, n_edges, nb, id * CH,
              sh.p.hist, sh.p.ofs, sh.p.gbase, sh.p.lcur, sh.p.tsum, sh.p.srec);
  }
}

// ---------------- standalone GEMM (fallback path only) ----------------
__global__ __launch_bounds__(256) void mfma_gemm_kernel(
    const float* __restrict__ x, const u16* __restrict__ Wp,
    u16* __restrict__ hb, int n_nodes) {
  __shared__ u16 xl[128 * 136];
  gemm_body(x, Wp, hb, n_nodes, blockIdx.x * 128, xl);
}

// ---------------- pass 2: quarter-wave dwordx4 gather-accumulate ----------------
// Quarter q (16 lanes) of wave w owns local rows [w*8+2q, w*8+2q+2): a
// contiguous, row-sorted srt segment. Per record, the quarter reads the full
// 256B h-row as 16x dwordx4 -> one wave-level VMEM instruction covers 4
// records (one per quarter). Unroll 4 -> 16 records in flight per wave.
__global__ __launch_bounds__(1024, 6) void bucket_accum_kernel(
    const u16* __restrict__ hb, const u64* __restrict__ reg,
    const int* __restrict__ gcur, float* __restrict__ out, int n_nodes) {
  __shared__ int hist[RB];
  __shared__ int ofs[RB];
  __shared__ int lcur[RB];
  __shared__ u64 srt[REG_CAP];

  const int t = threadIdx.x;
  const int b = blockIdx.x;
  const int row0 = b * RB;

  int n_e = gcur[b];
  if (n_e > REG_CAP) n_e = REG_CAP;

  if (t < RB) { hist[t] = 0; lcur[t] = 0; }
  __syncthreads();

  // load region once (coalesced, LLC-resident), histogram by local row
  u64 rr[3];
  int rl[3];
  bool ok[3];
#pragma unroll
  for (int i = 0; i < 3; ++i) {
    int j = i * 1024 + t;
    ok[i] = j < n_e;
    rr[i] = ok[i] ? reg[(size_t)b * REG_CAP + j] : 0;
    rl[i] = (int)(rr[i] >> 33) & (RB - 1);
    if (ok[i]) atomicAdd(&hist[rl[i]], 1);
  }
  __syncthreads();

  // exclusive scan of RB=128 entries by wave 0: 2 entries/lane shuffle scan
  if (t < 64) {
    int h0 = hist[2 * t], h1 = hist[2 * t + 1];
    int s = h0 + h1;
    int v = s;
#pragma unroll
    for (int off = 1; off < 64; off <<= 1) {
      int u = __shfl_up(v, off, 64);
      if (t >= off) v += u;
    }
    int ex = v - s;  // exclusive prefix of pair-sums
    ofs[2 * t] = ex;
    ofs[2 * t + 1] = ex + h0;
  }
  __syncthreads();

  // scatter records into row-sorted LDS order
#pragma unroll
  for (int i = 0; i < 3; ++i) {
    if (ok[i]) {
      int pos = ofs[rl[i]] + atomicAdd(&lcur[rl[i]], 1);
      srt[pos] = rr[i];
    }
  }
  __syncthreads();

  const int lane = t & 63;
  const int w = t >> 6;       // wave 0..15
  const int q = lane >> 4;    // quarter 0..3
  const int li = lane & 15;   // lane-in-quarter 0..15
  const int r0 = w * 8 + q * 2;  // this quarter's first local row

  const uint4* h4 = (const uint4*)hb;  // h row = 16 uint4 (256 B)
  float4* out4 = (float4*)out;         // out row = 32 float4 (512 B)

  // zero-fill this quarter's empty rows (streaming never flushes them)
#pragma unroll
  for (int k = 0; k < 2; ++k) {
    int rli = r0 + k;
    int gr = row0 + rli;
    if (gr < n_nodes && hist[rli] == 0) {
      out4[(size_t)gr * 32 + li * 2] = make_float4(0.f, 0.f, 0.f, 0.f);
      out4[(size_t)gr * 32 + li * 2 + 1] = make_float4(0.f, 0.f, 0.f, 0.f);
    }
  }

  int qs0 = ofs[r0];
  int qs1 = ofs[r0 + 1] + hist[r0 + 1];

  if (qs1 > qs0) {
    float a0 = 0.f, a1 = 0.f, a2 = 0.f, a3 = 0.f;
    float a4 = 0.f, a5 = 0.f, a6 = 0.f, a7 = 0.f;
    int cur = (int)(srt[qs0] >> 33) & (RB - 1);

    for (int p = qs0; p < qs1; p += 4) {
      // issue: 4 VMEM (each instruction gathers 4 records wave-wide)
      uint4 uu[4];
      unsigned mv[4];
#pragma unroll
      for (int j = 0; j < 4; ++j) {
        int idx = p + j;
        idx = idx < qs1 ? idx : qs1 - 1;  // clamp: duplicate gather, masked below
        u64 rec = srt[idx];               // 4 distinct LDS addrs/wave (broadcast per quarter)
        int col = (int)((rec >> 16) & 0x1FFFF);
        mv[j] = ((unsigned)((rec >> 33) & (RB - 1)) << 16) | (unsigned)(rec & 0xFFFF);
        uu[j] = h4[(size_t)col * 16 + li];
      }
      // consume
#pragma unroll
      for (int j = 0; j < 4; ++j) {
        if (p + j < qs1) {  // quarter-uniform predicate
          int lr = (int)(mv[j] >> 16);
          if (lr != cur) {  // quarter-uniform row transition: flush
            size_t o = (size_t)(row0 + cur) * 32 + li * 2;
            out4[o] = make_float4(a0, a1, a2, a3);
            out4[o + 1] = make_float4(a4, a5, a6, a7);
            a0 = a1 = a2 = a3 = a4 = a5 = a6 = a7 = 0.f;
            cur = lr;
          }
          float vv = h2f((u16)(mv[j] & 0xFFFF));
          a0 += vv * bf_lo(uu[j].x);
          a1 += vv * bf_hi(uu[j].x);
          a2 += vv * bf_lo(uu[j].y);
          a3 += vv * bf_hi(uu[j].y);
          a4 += vv * bf_lo(uu[j].z);
          a5 += vv * bf_hi(uu[j].z);
          a6 += vv * bf_lo(uu[j].w);
          a7 += vv * bf_hi(uu[j].w);
        }
      }
    }
    // final flush
    size_t o = (size_t)(row0 + cur) * 32 + li * 2;
    out4[o] = make_float4(a0, a1, a2, a3);
    out4[o + 1] = make_float4(a4, a5, a6, a7);
  }
}

// ---------------- fallback (atomic scatter on bf16 h) ----------------
__global__ __launch_bounds__(256) void scatter_kernel(
    const u16* __restrict__ hb, const float* __restrict__ vals,
    const int* __restrict__ rows, const int* __restrict__ cols,
    float* __restrict__ out, int n_edges) {
  const int lane = threadIdx.x & 63;
  const int wid = (blockIdx.x * blockDim.x + threadIdx.x) >> 6;
  const int nwaves = (gridDim.x * blockDim.x) >> 6;
  const unsigned* h32 = (const unsigned*)hb;
  for (int e = wid; e < n_edges; e += nwaves) {
    int r = rows[e];
    int c = cols[e];
    float v = vals[e];
    unsigned u = h32[(size_t)c * 64 + lane];
    float* op = out + (size_t)r * DIM + 2 * lane;
    atomicAdd(op, v * bf_lo(u));
    atomicAdd(op + 1, v * bf_hi(u));
  }
}

extern "C" void kernel_launch(void* const* d_in, const int* in_sizes, int n_in,
                              void* d_out, int out_size, void* d_ws, size_t ws_size,
                              hipStream_t stream) {
  const float* x = (const float*)d_in[0];
  const float* W = (const float*)d_in[1];
  const float* edge_vals = (const float*)d_in[2];
  const int* edge_rows = (const int*)d_in[3];
  const int* edge_cols = (const int*)d_in[4];
  float* out = (float*)d_out;

  const int n_nodes = in_sizes[0] / DIM;
  const int n_edges = in_sizes[2];
  const int nb = (n_nodes + RB - 1) / RB;

  // ws layout (16B-aligned chunks)
  char* p = (char*)d_ws;
  u16* hb = (u16*)p;   p += (((size_t)n_nodes * DIM * 2 + 15) / 16) * 16;  // 25.6 MB
  u16* Wp = (u16*)p;   p += (size_t)DIM * DIM * 2;                         // 32 KB
  int* gcur = (int*)p; p += (((size_t)nb * 4 + 15) / 16) * 16;             // ~3 KB
  u64* reg = (u64*)p;  p += (size_t)nb * REG_CAP * 8;                      // ~16 MB
  const size_t need = (size_t)(p - (char*)d_ws);

  repack_w_kernel<<<64, 256, 0, stream>>>(W, Wp);

  if (ws_size < need || nb > NB_MAX) {
    mfma_gemm_kernel<<<(n_nodes + 127) / 128, 256, 0, stream>>>(x, Wp, hb, n_nodes);
    hipMemsetAsync(d_out, 0, (size_t)out_size * sizeof(float), stream);
    scatter_kernel<<<2048, 256, 0, stream>>>(hb, edge_vals, edge_rows, edge_cols,
                                             out, n_edges);
    return;
  }

  hipMemsetAsync(gcur, 0, (size_t)nb * sizeof(int), stream);

  const int gA = (n_nodes + 127) / 128;
  const int gP = (n_edges + CH - 1) / CH;
  gemm_part_kernel<<<gA + gP, 256, 0, stream>>>(x, Wp, hb, edge_rows, edge_cols,
                                                edge_vals, gcur, reg, n_nodes,
                                                n_edges, nb, gA, gP);

  bucket_accum_kernel<<<nb, 1024, 0, stream>>>(hb, reg, gcur, out, n_nodes);
}